// Round 12
// baseline (431.806 us; speedup 1.0000x reference)
//
#include <hip/hip_runtime.h>
#include <hip/hip_bf16.h>

#define N_NODES 100000
#define N_EDGES 1600000
#define DIM 128
#define ODIM 16
#define NB 391           // coarse buckets: node >> 8
#define PCHUNK 3200      // edges per partition/hist block
#define PBLK 500         // 500*3200 = 1.6M exactly
#define FCAP 6144        // fine-sort LDS capacity (bucket mean 4096, std 64 -> 32 sigma)

typedef unsigned int uint32;
typedef float f32x4 __attribute__((ext_vector_type(4)));
typedef short bf16x8 __attribute__((ext_vector_type(8)));

static __device__ __forceinline__ float bflo(uint32 p) { return __uint_as_float(p << 16); }
static __device__ __forceinline__ float bfhi(uint32 p) { return __uint_as_float(p & 0xFFFF0000u); }
static __device__ __forceinline__ unsigned short f2bf(float f) {
  __hip_bfloat16 h = __float2bfloat16(f);
  return *reinterpret_cast<unsigned short*>(&h);
}
static __device__ __forceinline__ uint32 pk2bf(float a, float b) {
  return (uint32)f2bf(a) | ((uint32)f2bf(b) << 16);
}

// ===========================================================================
// Coarse bucket histogram (LDS-aggregated) -> bcnt[NB].
// ===========================================================================
__global__ __launch_bounds__(256) void bucket_hist_kernel(
    const int* __restrict__ dst, int* __restrict__ bcnt) {
  __shared__ int h[NB];
  int tid = threadIdx.x;
  for (int i = tid; i < NB; i += 256) h[i] = 0;
  __syncthreads();
  int e0 = blockIdx.x * PCHUNK;
  for (int i = tid; i < PCHUNK; i += 256) atomicAdd(&h[dst[e0 + i] >> 8], 1);
  __syncthreads();
  for (int i = tid; i < NB; i += 256)
    if (h[i]) atomicAdd(&bcnt[i], h[i]);
}

// One block: exclusive scan of bcnt -> bbase, bcur.
__global__ __launch_bounds__(512) void bucket_scan_kernel(
    const int* __restrict__ bcnt, int* __restrict__ bbase,
    int* __restrict__ bcur) {
  __shared__ int sc[512];
  int t = threadIdx.x;
  int v = (t < NB) ? bcnt[t] : 0;
  sc[t] = v;
  __syncthreads();
  for (int off = 1; off < 512; off <<= 1) {
    int a = (t >= off) ? sc[t - off] : 0;
    __syncthreads();
    sc[t] += a;
    __syncthreads();
  }
  if (t < NB) {
    int base = sc[t] - v;
    bbase[t] = base;
    bcur[t] = base;
  }
}

// ===========================================================================
// Coarse partition: bin edges by (dst>>8) with LDS staging, flush run-wise
// coalesced. Entry: x = src | ((dst&255)<<20), y = bits(weight).
// ===========================================================================
__global__ __launch_bounds__(256) void coarse_partition_kernel(
    const int* __restrict__ src, const int* __restrict__ dst,
    const float* __restrict__ ew, int* __restrict__ bcur,
    int2* __restrict__ epack) {
  __shared__ int hist[NB];
  __shared__ int base_a[NB];
  __shared__ int lcur_a[NB];
  __shared__ int gbase_a[NB];
  __shared__ int2 stg[PCHUNK];
  __shared__ int gpos[PCHUNK];

  int tid = threadIdx.x;
  int e0 = blockIdx.x * PCHUNK;

  for (int i = tid; i < NB; i += 256) hist[i] = 0;
  __syncthreads();
  for (int i = tid; i < PCHUNK; i += 256) atomicAdd(&hist[dst[e0 + i] >> 8], 1);
  __syncthreads();

  // wave-0 exclusive scan over NB buckets
  if (tid < 64) {
    int run = 0;
#pragma unroll
    for (int c = 0; c < 7; c++) {
      int idx = c * 64 + tid;
      int v = (idx < NB) ? hist[idx] : 0;
      int incl = v;
#pragma unroll
      for (int off = 1; off < 64; off <<= 1) {
        int tv = __shfl_up(incl, off, 64);
        if (tid >= off) incl += tv;
      }
      if (idx < NB) base_a[idx] = run + incl - v;
      run += __shfl(incl, 63, 64);
    }
  }
  __syncthreads();
  for (int i = tid; i < NB; i += 256) {
    int c = hist[i];
    gbase_a[i] = (c > 0) ? atomicAdd(&bcur[i], c) : 0;
    lcur_a[i] = base_a[i];
  }
  __syncthreads();

  for (int i = tid; i < PCHUNK; i += 256) {
    int e = e0 + i;
    int s = src[e], d = dst[e];
    float w = ew[e];
    int b = d >> 8;
    int pos = atomicAdd(&lcur_a[b], 1);
    stg[pos] = make_int2(s | ((d & 255) << 20), __float_as_int(w));
    gpos[pos] = gbase_a[b] + (pos - base_a[b]);
  }
  __syncthreads();
  for (int i = tid; i < PCHUNK; i += 256) epack[gpos[i]] = stg[i];
}

// ===========================================================================
// Fine sort (in-place) + row_ptr build: one block per coarse bucket.
// Output entry: x = src, y = weight bits. LDS = 52.2 KB.
// ===========================================================================
__global__ __launch_bounds__(256) void fine_sort_kernel(
    const int* __restrict__ bbase, int2* __restrict__ epack,
    int* __restrict__ row_ptr) {
  __shared__ int2 ebuf[FCAP];
  __shared__ int hist[256];
  __shared__ int sc[256];
  __shared__ int cur[256];
  int tid = threadIdx.x;
  int b = blockIdx.x;
  int node0 = b << 8;
  int lo = bbase[b];
  int hi = (b == NB - 1) ? N_EDGES : bbase[b + 1];
  int n = hi - lo;
  if (n > FCAP) n = FCAP;   // statistically impossible (32 sigma)
  hist[tid] = 0;
  __syncthreads();
  for (int i = tid; i < n; i += 256) {
    int2 e = epack[lo + i];
    ebuf[i] = e;
    atomicAdd(&hist[(e.x >> 20) & 255], 1);
  }
  __syncthreads();
  sc[tid] = hist[tid];
  __syncthreads();
  for (int off = 1; off < 256; off <<= 1) {
    int a = (tid >= off) ? sc[tid - off] : 0;
    __syncthreads();
    sc[tid] += a;
    __syncthreads();
  }
  int rp = lo + sc[tid] - hist[tid];   // exclusive
  if (node0 + tid < N_NODES) row_ptr[node0 + tid] = rp;
  cur[tid] = rp;
  if (b == 0 && tid == 0) row_ptr[N_NODES] = N_EDGES;
  __syncthreads();
  for (int i = tid; i < n; i += 256) {
    int2 e = ebuf[i];
    int pos = atomicAdd(&cur[(e.x >> 20) & 255], 1);
    epack[pos] = make_int2(e.x & 0xFFFFF, e.y);
  }
}

// ===========================================================================
// Cast x (f32, N x 128) -> packed bf16 pairs (N x 64 uints).
// ===========================================================================
__global__ __launch_bounds__(256) void cast_x_kernel(
    const float2* __restrict__ x2, uint32* __restrict__ Xu) {
  int i = blockIdx.x * 256 + threadIdx.x;
  if (i < N_NODES * (DIM / 2)) {
    float2 v = x2[i];
    Xu[i] = pk2bf(v.x, v.y);
  }
}

// ===========================================================================
// Pack W (f32 K x N) into MFMA B-fragment order, bf16.
// ===========================================================================
__global__ __launch_bounds__(256) void packW128_kernel(
    const float* __restrict__ W, unsigned short* __restrict__ out) {
  int idx = blockIdx.x * 256 + threadIdx.x;          // 16384
  int j = idx & 7, lane = (idx >> 3) & 63, nt = (idx >> 9) & 7, kc = idx >> 12;
  int k = kc * 32 + (lane >> 4) * 8 + j;
  int n = nt * 16 + (lane & 15);
  out[idx] = f2bf(W[k * DIM + n]);
}

__global__ __launch_bounds__(256) void packW16_kernel(
    const float* __restrict__ W, unsigned short* __restrict__ out) {
  int idx = blockIdx.x * 256 + threadIdx.x;          // 2048
  if (idx >= 2048) return;
  int j = idx & 7, lane = (idx >> 3) & 63, kc = idx >> 9;
  int k = kc * 32 + (lane >> 4) * 8 + j;
  int n = lane & 15;
  out[idx] = f2bf(W[k * ODIM + n]);
}

// ===========================================================================
// Fused GIN layer: gather (v3 loop, proven in r11) -> U = (1+eps)x+agg ->
// LDS A-tile -> MFMA (B frags from global, L2-hot) -> bias/relu/L2norm ->
// bf16 Hout (+ optional fused y = Hnorm @ W2).
// Wave w gathers exactly the 16 A-rows its own MFMA consumes: no barrier
// between gather and MFMA; single block barrier before cooperative copy-out.
// #pragma unroll 1 on the node loop caps code size (compile-time safety).
// LDS = 17.4 KB only.
// ===========================================================================
template <int FUSE_PROJ>
__global__ __launch_bounds__(256) void gin_fused(
    const uint32* __restrict__ Hin, const int* __restrict__ row_ptr,
    const int2* __restrict__ ep, const unsigned char* __restrict__ pW,
    const float* __restrict__ b, const float* __restrict__ eps_p,
    uint32* __restrict__ Hout,
    const unsigned char* __restrict__ pW2, float* __restrict__ y) {
  __shared__ __align__(16) unsigned char As[64 * 272];   // 17408 B
  int tid = threadIdx.x;
  int node0 = blockIdx.x * 64;
  int w = tid >> 6, l = tid & 63;
  int grp = l >> 4, l4 = l & 15;
  float epf = 1.0f + *eps_p;
  int nbase = node0 + w * 16;

  // preload this wave's 17 row_ptr entries into lanes (clamped)
  int rpl;
  {
    int qi = nbase + (l < 17 ? l : 16);
    qi = qi < N_NODES ? qi : N_NODES;
    rpl = row_ptr[qi];
  }

  // ---- gather phase: 16 nodes per wave (loop NOT unrolled) ----
#pragma unroll 1
  for (int n = 0; n < 16; n++) {
    int a = __shfl(rpl, n, 64);
    int bnd = __shfl(rpl, n + 1, 64);
    float acc[8];
#pragma unroll
    for (int k = 0; k < 8; k++) acc[k] = 0.f;

    auto pass4 = [&](int jj) {
      int2 e = ep[jj + grp];
      uint4 p = *(const uint4*)(Hin + (size_t)e.x * 64 + l4 * 4);
      float wv = __int_as_float(e.y);
      acc[0] = fmaf(wv, bflo(p.x), acc[0]); acc[1] = fmaf(wv, bfhi(p.x), acc[1]);
      acc[2] = fmaf(wv, bflo(p.y), acc[2]); acc[3] = fmaf(wv, bfhi(p.y), acc[3]);
      acc[4] = fmaf(wv, bflo(p.z), acc[4]); acc[5] = fmaf(wv, bfhi(p.z), acc[5]);
      acc[6] = fmaf(wv, bflo(p.w), acc[6]); acc[7] = fmaf(wv, bfhi(p.w), acc[7]);
    };

    int j = a;
#pragma unroll 1
    for (; j + 8 <= bnd; j += 8) { pass4(j); pass4(j + 4); }
    if (j + 4 <= bnd) { pass4(j); j += 4; }
    if (j < bnd) {   // masked tail (<4 edges; bnd>=1 guaranteed here)
      int idx = j + grp;
      int vld = idx < bnd;
      int2 e = ep[vld ? idx : bnd - 1];
      uint4 p = *(const uint4*)(Hin + (size_t)e.x * 64 + l4 * 4);
      float wv = vld ? __int_as_float(e.y) : 0.f;
      acc[0] = fmaf(wv, bflo(p.x), acc[0]); acc[1] = fmaf(wv, bfhi(p.x), acc[1]);
      acc[2] = fmaf(wv, bflo(p.y), acc[2]); acc[3] = fmaf(wv, bfhi(p.y), acc[3]);
      acc[4] = fmaf(wv, bflo(p.z), acc[4]); acc[5] = fmaf(wv, bfhi(p.z), acc[5]);
      acc[6] = fmaf(wv, bflo(p.w), acc[6]); acc[7] = fmaf(wv, bfhi(p.w), acc[7]);
    }
    // combine the 4 edge-groups
#pragma unroll
    for (int k = 0; k < 8; k++) {
      acc[k] += __shfl_xor(acc[k], 16, 64);
      acc[k] += __shfl_xor(acc[k], 32, 64);
    }
    // own-row term + pack + LDS write (lanes 0-15 cover the full row)
    int node = nbase + n;
    int cn = node < N_NODES ? node : N_NODES - 1;
    uint4 own = *(const uint4*)(Hin + (size_t)cn * 64 + l4 * 4);
    uint32 o0 = pk2bf(fmaf(epf, bflo(own.x), acc[0]), fmaf(epf, bfhi(own.x), acc[1]));
    uint32 o1 = pk2bf(fmaf(epf, bflo(own.y), acc[2]), fmaf(epf, bfhi(own.y), acc[3]));
    uint32 o2 = pk2bf(fmaf(epf, bflo(own.z), acc[4]), fmaf(epf, bfhi(own.z), acc[5]));
    uint32 o3 = pk2bf(fmaf(epf, bflo(own.w), acc[6]), fmaf(epf, bfhi(own.w), acc[7]));
    if (l < 16) {
      uint4 st = {o0, o1, o2, o3};
      *(uint4*)(As + (w * 16 + n) * 272 + l4 * 16) = st;
    }
  }

  // ---- MFMA phase (reads only this wave's 16 LDS rows; B from global) ----
  int m = l & 15, q = l >> 4;
  f32x4 acc2[8];
#pragma unroll
  for (int nt = 0; nt < 8; nt++) acc2[nt] = (f32x4){0.f, 0.f, 0.f, 0.f};
  const unsigned char* Abase = As + (w * 16 + m) * 272 + q * 16;
#pragma unroll
  for (int kc = 0; kc < 4; kc++) {
    bf16x8 af = *(const bf16x8*)(Abase + kc * 64);
#pragma unroll
    for (int nt = 0; nt < 8; nt++) {
      bf16x8 bfr = *(const bf16x8*)(pW + (size_t)((kc * 8 + nt) * 64 + l) * 16);
      acc2[nt] = __builtin_amdgcn_mfma_f32_16x16x32_bf16(af, bfr, acc2[nt], 0, 0, 0);
    }
  }

  // ---- epilogue: bias + relu + L2 norm (C row = node q*4+r, col = nt*16+m) ----
  float ss[4] = {0.f, 0.f, 0.f, 0.f};
#pragma unroll
  for (int nt = 0; nt < 8; nt++) {
    float bj = b[nt * 16 + m];
#pragma unroll
    for (int r = 0; r < 4; r++) {
      float v = fmaxf(acc2[nt][r] + bj, 0.0f);
      acc2[nt][r] = v;
      ss[r] += v * v;
    }
  }
#pragma unroll
  for (int r = 0; r < 4; r++) {
    float s = ss[r];
    s += __shfl_xor(s, 1, 64);
    s += __shfl_xor(s, 2, 64);
    s += __shfl_xor(s, 4, 64);
    s += __shfl_xor(s, 8, 64);
    ss[r] = 1.0f / fmaxf(sqrtf(s), 1e-12f);
  }
  // write normalized bf16 back into this wave's own As rows
#pragma unroll
  for (int nt = 0; nt < 8; nt++) {
#pragma unroll
    for (int r = 0; r < 4; r++) {
      unsigned short hv = f2bf(acc2[nt][r] * ss[r]);
      *(unsigned short*)(As + (w * 16 + q * 4 + r) * 272 + (nt * 16 + m) * 2) = hv;
    }
  }

  // ---- optional fused projection y = Hnorm @ W2 (own rows, no barrier) ----
  if (FUSE_PROJ) {
    f32x4 accy = (f32x4){0.f, 0.f, 0.f, 0.f};
#pragma unroll
    for (int kc = 0; kc < 4; kc++) {
      bf16x8 af = *(const bf16x8*)(Abase + kc * 64);
      bf16x8 bfr = *(const bf16x8*)(pW2 + (size_t)(kc * 64 + l) * 16);
      accy = __builtin_amdgcn_mfma_f32_16x16x32_bf16(af, bfr, accy, 0, 0, 0);
    }
#pragma unroll
    for (int r = 0; r < 4; r++) {
      int orow = node0 + w * 16 + q * 4 + r;
      if (orow < N_NODES) y[(size_t)orow * ODIM + m] = accy[r];
    }
  }

  __syncthreads();   // all waves' normalized rows in As
  int rem = N_NODES - node0; if (rem > 64) rem = 64;
  for (int i = tid; i < 1024; i += 256) {
    int row = i >> 4, seg = i & 15;
    if (row < rem) {
      uint4 vv = *(const uint4*)(As + row * 272 + seg * 16);
      *(uint4*)((unsigned char*)Hout + (size_t)(node0 + row) * 256 + seg * 16) = vv;
    }
  }
}

// ===========================================================================
// Fused: aggy = gather16(y); logits = relu((1+eps)*y + aggy + b);
// probs = softmax. Wave per node (4/block); quarters split the edge list.
// (r8/r11-proven version)
// ===========================================================================
__global__ __launch_bounds__(256) void gather16_final_kernel(
    const float* __restrict__ y, const int* __restrict__ row_ptr,
    const int2* __restrict__ ep, const float* __restrict__ b,
    const float* __restrict__ eps_p, float* __restrict__ out_logits,
    float* __restrict__ out_probs) {
  int lane = threadIdx.x & 63;
  int node = blockIdx.x * 4 + (threadIdx.x >> 6);
  if (node >= N_NODES) return;
  int f = lane & 15, eq = lane >> 4;
  int a = row_ptr[node], bnd = row_ptr[node + 1];
  float acc = 0.0f;
  int j = a + eq;
  for (; j + 8 <= bnd; j += 8) {
    int s0 = ep[j].x, s1 = ep[j + 4].x;
    acc += y[(size_t)s0 * ODIM + f] + y[(size_t)s1 * ODIM + f];
  }
  for (; j < bnd; j += 4) acc += y[(size_t)ep[j].x * ODIM + f];
  acc += __shfl_xor(acc, 16, 64);
  acc += __shfl_xor(acc, 32, 64);
  if (eq == 0) {
    float epf = 1.0f + *eps_p;
    size_t idx = (size_t)node * ODIM + f;
    float logit = fmaxf(fmaf(epf, y[idx], acc) + b[f], 0.0f);
    float mx = logit;
#pragma unroll
    for (int mm = 8; mm >= 1; mm >>= 1) mx = fmaxf(mx, __shfl_xor(mx, mm, 16));
    float e = __expf(logit - mx);
    float ssum = e;
#pragma unroll
    for (int mm = 8; mm >= 1; mm >>= 1) ssum += __shfl_xor(ssum, mm, 16);
    out_logits[idx] = logit;
    out_probs[idx] = e / ssum;
  }
}

// ===========================================================================
extern "C" void kernel_launch(void* const* d_in, const int* in_sizes, int n_in,
                              void* d_out, int out_size, void* d_ws, size_t ws_size,
                              hipStream_t stream) {
  const float* x = (const float*)d_in[0];
  const int* ei = (const int*)d_in[1];       // int64 in reference -> int32 on device
  const float* ew = (const float*)d_in[2];
  const float* W0 = (const float*)d_in[3];
  const float* b0 = (const float*)d_in[4];
  const float* e0 = (const float*)d_in[5];
  const float* W1 = (const float*)d_in[6];
  const float* b1 = (const float*)d_in[7];
  const float* e1 = (const float*)d_in[8];
  const float* W2 = (const float*)d_in[9];
  const float* b2 = (const float*)d_in[10];
  const float* e2 = (const float*)d_in[11];
  float* out = (float*)d_out;

  const int* srcp = ei;
  const int* dstp = ei + N_EDGES;

  // ---- workspace layout (~96.3 MB; 102.4 MB proven available) ----
  char* ws = (char*)d_ws;
  size_t off = 0;
  uint32* Xb  = (uint32*)(ws + off);  off += (size_t)N_NODES * DIM * 2;   // 25.6 MB
  uint32* H0  = (uint32*)(ws + off);  off += (size_t)N_NODES * DIM * 2;   // 25.6 MB
  uint32* H1  = (uint32*)(ws + off);  off += (size_t)N_NODES * DIM * 2;   // 25.6 MB
  int2* epack = (int2*)(ws + off);    off += (size_t)N_EDGES * 8;         // 12.8 MB
  float* y    = (float*)(ws + off);   off += (size_t)N_NODES * ODIM * 4;  // 6.4 MB
  int* row_ptr = (int*)(ws + off);    off += (size_t)(N_NODES + 16) * 4;
  int* bcnt   = (int*)(ws + off);     off += 2048;
  int* bbase  = (int*)(ws + off);     off += 2048;
  int* bcur   = (int*)(ws + off);     off += 2048;
  unsigned short* pW0 = (unsigned short*)(ws + off); off += 32768;
  unsigned short* pW1 = (unsigned short*)(ws + off); off += 32768;
  unsigned short* pW2 = (unsigned short*)(ws + off); off += 4096;

  // ---- independent prep: cast x, pack weights ----
  cast_x_kernel<<<(N_NODES * (DIM / 2) + 255) / 256, 256, 0, stream>>>(
      (const float2*)x, Xb);
  packW128_kernel<<<64, 256, 0, stream>>>(W0, pW0);
  packW128_kernel<<<64, 256, 0, stream>>>(W1, pW1);
  packW16_kernel<<<8, 256, 0, stream>>>(W2, pW2);

  // ---- build CSR: bucket hist -> scan -> coarse partition -> fine sort ----
  hipMemsetAsync(bcnt, 0, NB * sizeof(int), stream);
  bucket_hist_kernel<<<PBLK, 256, 0, stream>>>(dstp, bcnt);
  bucket_scan_kernel<<<1, 512, 0, stream>>>(bcnt, bbase, bcur);
  coarse_partition_kernel<<<PBLK, 256, 0, stream>>>(srcp, dstp, ew, bcur, epack);
  fine_sort_kernel<<<NB, 256, 0, stream>>>(bbase, epack, row_ptr);

  int mgrid = (N_NODES + 63) / 64;     // 1563
  int ggrid = (N_NODES + 3) / 4;       // 25000

  // layer 0 fused: H0 = norm(relu(((1+e0)Xb + gather(Xb)) @ W0 + b0))
  gin_fused<0><<<mgrid, 256, 0, stream>>>(Xb, row_ptr, epack,
                                          (const unsigned char*)pW0, b0, e0,
                                          H0, nullptr, nullptr);
  // layer 1 fused (+ layer-2 projection): H1, y
  gin_fused<1><<<mgrid, 256, 0, stream>>>(H0, row_ptr, epack,
                                          (const unsigned char*)pW1, b1, e1,
                                          H1, (const unsigned char*)pW2, y);
  // layer 2 tail: fused gather16 + bias/relu/softmax
  gather16_final_kernel<<<ggrid, 256, 0, stream>>>(y, row_ptr, epack, b2, e2,
                                                   out, out + (size_t)N_NODES * ODIM);
}

// Round 13
// 394.062 us; speedup vs baseline: 1.0958x; 1.0958x over previous
//
#include <hip/hip_runtime.h>
#include <hip/hip_bf16.h>

#define N_NODES 100000
#define N_EDGES 1600000
#define DIM 128
#define ODIM 16
#define NB 391           // coarse buckets: node >> 8
#define PCHUNK 3200      // edges per partition/hist block
#define PBLK 500         // 500*3200 = 1.6M exactly
#define FCAP 6144        // fine-sort LDS capacity (bucket mean 4096, std 64 -> 32 sigma)

typedef unsigned int uint32;
typedef float f32x4 __attribute__((ext_vector_type(4)));
typedef short bf16x8 __attribute__((ext_vector_type(8)));

static __device__ __forceinline__ float bflo(uint32 p) { return __uint_as_float(p << 16); }
static __device__ __forceinline__ float bfhi(uint32 p) { return __uint_as_float(p & 0xFFFF0000u); }
static __device__ __forceinline__ unsigned short f2bf(float f) {
  __hip_bfloat16 h = __float2bfloat16(f);
  return *reinterpret_cast<unsigned short*>(&h);
}
static __device__ __forceinline__ uint32 pk2bf(float a, float b) {
  return (uint32)f2bf(a) | ((uint32)f2bf(b) << 16);
}

// ===========================================================================
// Coarse bucket histogram (LDS-aggregated) -> bcnt[NB].
// ===========================================================================
__global__ __launch_bounds__(256) void bucket_hist_kernel(
    const int* __restrict__ dst, int* __restrict__ bcnt) {
  __shared__ int h[NB];
  int tid = threadIdx.x;
  for (int i = tid; i < NB; i += 256) h[i] = 0;
  __syncthreads();
  int e0 = blockIdx.x * PCHUNK;
  for (int i = tid; i < PCHUNK; i += 256) atomicAdd(&h[dst[e0 + i] >> 8], 1);
  __syncthreads();
  for (int i = tid; i < NB; i += 256)
    if (h[i]) atomicAdd(&bcnt[i], h[i]);
}

// One block: exclusive scan of bcnt -> bbase, bcur.
__global__ __launch_bounds__(512) void bucket_scan_kernel(
    const int* __restrict__ bcnt, int* __restrict__ bbase,
    int* __restrict__ bcur) {
  __shared__ int sc[512];
  int t = threadIdx.x;
  int v = (t < NB) ? bcnt[t] : 0;
  sc[t] = v;
  __syncthreads();
  for (int off = 1; off < 512; off <<= 1) {
    int a = (t >= off) ? sc[t - off] : 0;
    __syncthreads();
    sc[t] += a;
    __syncthreads();
  }
  if (t < NB) {
    int base = sc[t] - v;
    bbase[t] = base;
    bcur[t] = base;
  }
}

// ===========================================================================
// Coarse partition: bin edges by (dst>>8) with LDS staging, flush run-wise
// coalesced. Entry: x = src | ((dst&255)<<20), y = bits(weight).
// ===========================================================================
__global__ __launch_bounds__(256) void coarse_partition_kernel(
    const int* __restrict__ src, const int* __restrict__ dst,
    const float* __restrict__ ew, int* __restrict__ bcur,
    int2* __restrict__ epack) {
  __shared__ int hist[NB];
  __shared__ int base_a[NB];
  __shared__ int lcur_a[NB];
  __shared__ int gbase_a[NB];
  __shared__ int2 stg[PCHUNK];
  __shared__ int gpos[PCHUNK];

  int tid = threadIdx.x;
  int e0 = blockIdx.x * PCHUNK;

  for (int i = tid; i < NB; i += 256) hist[i] = 0;
  __syncthreads();
  for (int i = tid; i < PCHUNK; i += 256) atomicAdd(&hist[dst[e0 + i] >> 8], 1);
  __syncthreads();

  // wave-0 exclusive scan over NB buckets
  if (tid < 64) {
    int run = 0;
#pragma unroll
    for (int c = 0; c < 7; c++) {
      int idx = c * 64 + tid;
      int v = (idx < NB) ? hist[idx] : 0;
      int incl = v;
#pragma unroll
      for (int off = 1; off < 64; off <<= 1) {
        int tv = __shfl_up(incl, off, 64);
        if (tid >= off) incl += tv;
      }
      if (idx < NB) base_a[idx] = run + incl - v;
      run += __shfl(incl, 63, 64);
    }
  }
  __syncthreads();
  for (int i = tid; i < NB; i += 256) {
    int c = hist[i];
    gbase_a[i] = (c > 0) ? atomicAdd(&bcur[i], c) : 0;
    lcur_a[i] = base_a[i];
  }
  __syncthreads();

  for (int i = tid; i < PCHUNK; i += 256) {
    int e = e0 + i;
    int s = src[e], d = dst[e];
    float w = ew[e];
    int b = d >> 8;
    int pos = atomicAdd(&lcur_a[b], 1);
    stg[pos] = make_int2(s | ((d & 255) << 20), __float_as_int(w));
    gpos[pos] = gbase_a[b] + (pos - base_a[b]);
  }
  __syncthreads();
  for (int i = tid; i < PCHUNK; i += 256) epack[gpos[i]] = stg[i];
}

// ===========================================================================
// Fine sort (in-place) + row_ptr build: one block per coarse bucket.
// Output entry: x = src, y = weight bits. LDS = 52.2 KB.
// ===========================================================================
__global__ __launch_bounds__(256) void fine_sort_kernel(
    const int* __restrict__ bbase, int2* __restrict__ epack,
    int* __restrict__ row_ptr) {
  __shared__ int2 ebuf[FCAP];
  __shared__ int hist[256];
  __shared__ int sc[256];
  __shared__ int cur[256];
  int tid = threadIdx.x;
  int b = blockIdx.x;
  int node0 = b << 8;
  int lo = bbase[b];
  int hi = (b == NB - 1) ? N_EDGES : bbase[b + 1];
  int n = hi - lo;
  if (n > FCAP) n = FCAP;   // statistically impossible (32 sigma)
  hist[tid] = 0;
  __syncthreads();
  for (int i = tid; i < n; i += 256) {
    int2 e = epack[lo + i];
    ebuf[i] = e;
    atomicAdd(&hist[(e.x >> 20) & 255], 1);
  }
  __syncthreads();
  sc[tid] = hist[tid];
  __syncthreads();
  for (int off = 1; off < 256; off <<= 1) {
    int a = (tid >= off) ? sc[tid - off] : 0;
    __syncthreads();
    sc[tid] += a;
    __syncthreads();
  }
  int rp = lo + sc[tid] - hist[tid];   // exclusive
  if (node0 + tid < N_NODES) row_ptr[node0 + tid] = rp;
  cur[tid] = rp;
  if (b == 0 && tid == 0) row_ptr[N_NODES] = N_EDGES;
  __syncthreads();
  for (int i = tid; i < n; i += 256) {
    int2 e = ebuf[i];
    int pos = atomicAdd(&cur[(e.x >> 20) & 255], 1);
    epack[pos] = make_int2(e.x & 0xFFFFF, e.y);
  }
}

// ===========================================================================
// Cast x (f32, N x 128) -> packed bf16 pairs (N x 64 uints).
// ===========================================================================
__global__ __launch_bounds__(256) void cast_x_kernel(
    const float2* __restrict__ x2, uint32* __restrict__ Xu) {
  int i = blockIdx.x * 256 + threadIdx.x;
  if (i < N_NODES * (DIM / 2)) {
    float2 v = x2[i];
    Xu[i] = pk2bf(v.x, v.y);
  }
}

// ===========================================================================
// Pack W (f32 K x N) into MFMA B-fragment order, bf16.
// ===========================================================================
__global__ __launch_bounds__(256) void packW128_kernel(
    const float* __restrict__ W, unsigned short* __restrict__ out) {
  int idx = blockIdx.x * 256 + threadIdx.x;          // 16384
  int j = idx & 7, lane = (idx >> 3) & 63, nt = (idx >> 9) & 7, kc = idx >> 12;
  int k = kc * 32 + (lane >> 4) * 8 + j;
  int n = nt * 16 + (lane & 15);
  out[idx] = f2bf(W[k * DIM + n]);
}

__global__ __launch_bounds__(256) void packW16_kernel(
    const float* __restrict__ W, unsigned short* __restrict__ out) {
  int idx = blockIdx.x * 256 + threadIdx.x;          // 2048
  if (idx >= 2048) return;
  int j = idx & 7, lane = (idx >> 3) & 63, kc = idx >> 9;
  int k = kc * 32 + (lane >> 4) * 8 + j;
  int n = lane & 15;
  out[idx] = f2bf(W[k * ODIM + n]);
}

// ===========================================================================
// Gather v4: wave per node, uint4 row loads (16 lanes/row, 4 edges/instr).
// 16-edge main body: 4 ep loads then 4 independent row loads issued together
// (8 vmem in flight) before the FMA block -> ~2x per-wave throughput vs the
// ep->row serialized 8-edge loop. Mean degree 16 => one main iter per node.
// ===========================================================================
__global__ __launch_bounds__(256) void gather_bf16(
    const uint32* __restrict__ hu, const int* __restrict__ row_ptr,
    const int2* __restrict__ ep, uint32* __restrict__ aggu) {
  int lane = threadIdx.x & 63;
  int node = blockIdx.x * 4 + (threadIdx.x >> 6);
  if (node >= N_NODES) return;
  int grp = lane >> 4, l4 = lane & 15;
  int a = row_ptr[node], bnd = row_ptr[node + 1];
  float acc[8];
#pragma unroll
  for (int k = 0; k < 8; k++) acc[k] = 0.f;

  auto acc8 = [&](float wv, const uint4& p) {
    acc[0] = fmaf(wv, bflo(p.x), acc[0]); acc[1] = fmaf(wv, bfhi(p.x), acc[1]);
    acc[2] = fmaf(wv, bflo(p.y), acc[2]); acc[3] = fmaf(wv, bfhi(p.y), acc[3]);
    acc[4] = fmaf(wv, bflo(p.z), acc[4]); acc[5] = fmaf(wv, bfhi(p.z), acc[5]);
    acc[6] = fmaf(wv, bflo(p.w), acc[6]); acc[7] = fmaf(wv, bfhi(p.w), acc[7]);
  };

  int j = a;
#pragma unroll 1
  for (; j + 16 <= bnd; j += 16) {
    int2 e0 = ep[j + grp];
    int2 e1 = ep[j + 4 + grp];
    int2 e2 = ep[j + 8 + grp];
    int2 e3 = ep[j + 12 + grp];
    uint4 p0 = *(const uint4*)(hu + (size_t)e0.x * 64 + l4 * 4);
    uint4 p1 = *(const uint4*)(hu + (size_t)e1.x * 64 + l4 * 4);
    uint4 p2 = *(const uint4*)(hu + (size_t)e2.x * 64 + l4 * 4);
    uint4 p3 = *(const uint4*)(hu + (size_t)e3.x * 64 + l4 * 4);
    acc8(__int_as_float(e0.y), p0);
    acc8(__int_as_float(e1.y), p1);
    acc8(__int_as_float(e2.y), p2);
    acc8(__int_as_float(e3.y), p3);
  }
  if (j + 8 <= bnd) {
    int2 e0 = ep[j + grp];
    int2 e1 = ep[j + 4 + grp];
    uint4 p0 = *(const uint4*)(hu + (size_t)e0.x * 64 + l4 * 4);
    uint4 p1 = *(const uint4*)(hu + (size_t)e1.x * 64 + l4 * 4);
    acc8(__int_as_float(e0.y), p0);
    acc8(__int_as_float(e1.y), p1);
    j += 8;
  }
  if (j + 4 <= bnd) {
    int2 e0 = ep[j + grp];
    uint4 p0 = *(const uint4*)(hu + (size_t)e0.x * 64 + l4 * 4);
    acc8(__int_as_float(e0.y), p0);
    j += 4;
  }
  if (j < bnd) {   // masked tail (<4 edges; bnd>=1 guaranteed here)
    int idx = j + grp;
    int vld = idx < bnd;
    int2 e = ep[vld ? idx : bnd - 1];
    uint4 p = *(const uint4*)(hu + (size_t)e.x * 64 + l4 * 4);
    float wv = vld ? __int_as_float(e.y) : 0.f;
    acc8(wv, p);
  }
#pragma unroll
  for (int k = 0; k < 8; k++) {
    acc[k] += __shfl_xor(acc[k], 16, 64);
    acc[k] += __shfl_xor(acc[k], 32, 64);
  }
  if (lane < 16) {
    uint4 st = {pk2bf(acc[0], acc[1]), pk2bf(acc[2], acc[3]),
                pk2bf(acc[4], acc[5]), pk2bf(acc[6], acc[7])};
    *(uint4*)(aggu + (size_t)node * 64 + l4 * 4) = st;
  }
}

// ===========================================================================
// Fused GIN MLP via MFMA (bf16), 64 nodes x 128 outs per block.
// B fragments read straight from global (L2-hot, proven in r12) ->
// LDS = 17.4 KB only -> no LDS occupancy cap (was 3 blocks/CU at 50 KB).
// FUSE_PROJ=1 additionally emits y = H_norm @ W2 (128->16, fp32).
// ===========================================================================
template <int FUSE_PROJ>
__global__ __launch_bounds__(256) void gin_mlp_mfma(
    const uint32* Xu, const uint32* __restrict__ Au,
    const unsigned char* __restrict__ pW, const float* __restrict__ b,
    const float* __restrict__ eps_p, uint32* outH,
    const unsigned char* __restrict__ pW2, float* __restrict__ y) {
  __shared__ __align__(16) unsigned char As[64 * 272];   // 17408 B
  int tid = threadIdx.x;
  int node0 = blockIdx.x * 64;
  float epf = 1.0f + *eps_p;

  for (int i = tid; i < 64 * 64; i += 256) {
    int n = i >> 6, fp = i & 63;
    int node = node0 + n;
    int cn = node < N_NODES ? node : N_NODES - 1;
    size_t idx = (size_t)cn * 64 + fp;
    uint32 xv = Xu[idx], av = Au[idx];
    float u0 = fmaf(epf, bflo(xv), bflo(av));
    float u1 = fmaf(epf, bfhi(xv), bfhi(av));
    *(uint32*)(As + n * 272 + fp * 4) = pk2bf(u0, u1);
  }
  __syncthreads();

  int w = tid >> 6, l = tid & 63;
  int m = l & 15, q = l >> 4;

  f32x4 acc[8];
#pragma unroll
  for (int nt = 0; nt < 8; nt++) acc[nt] = (f32x4){0.f, 0.f, 0.f, 0.f};

  const unsigned char* Abase = As + (w * 16 + m) * 272 + q * 16;
#pragma unroll
  for (int kc = 0; kc < 4; kc++) {
    bf16x8 af = *(const bf16x8*)(Abase + kc * 64);
#pragma unroll
    for (int nt = 0; nt < 8; nt++) {
      bf16x8 bfr = *(const bf16x8*)(pW + (size_t)((kc * 8 + nt) * 64 + l) * 16);
      acc[nt] = __builtin_amdgcn_mfma_f32_16x16x32_bf16(af, bfr, acc[nt], 0, 0, 0);
    }
  }

  float ss[4] = {0.f, 0.f, 0.f, 0.f};
#pragma unroll
  for (int nt = 0; nt < 8; nt++) {
    float bj = b[nt * 16 + m];
#pragma unroll
    for (int r = 0; r < 4; r++) {
      float v = fmaxf(acc[nt][r] + bj, 0.0f);
      acc[nt][r] = v;
      ss[r] += v * v;
    }
  }
#pragma unroll
  for (int r = 0; r < 4; r++) {
    float s = ss[r];
    s += __shfl_xor(s, 1, 64);
    s += __shfl_xor(s, 2, 64);
    s += __shfl_xor(s, 4, 64);
    s += __shfl_xor(s, 8, 64);
    ss[r] = 1.0f / fmaxf(sqrtf(s), 1e-12f);
  }
  // write normalized bf16 back into this wave's own As rows (no barrier needed:
  // each wave reads/writes only its own 16-row band)
#pragma unroll
  for (int nt = 0; nt < 8; nt++) {
#pragma unroll
    for (int r = 0; r < 4; r++) {
      unsigned short hv = f2bf(acc[nt][r] * ss[r]);
      *(unsigned short*)(As + (w * 16 + q * 4 + r) * 272 + (nt * 16 + m) * 2) = hv;
    }
  }

  if (FUSE_PROJ) {
    f32x4 accy = (f32x4){0.f, 0.f, 0.f, 0.f};
#pragma unroll
    for (int kc = 0; kc < 4; kc++) {
      bf16x8 af = *(const bf16x8*)(Abase + kc * 64);   // normalized H tile
      bf16x8 bfr = *(const bf16x8*)(pW2 + (size_t)(kc * 64 + l) * 16);
      accy = __builtin_amdgcn_mfma_f32_16x16x32_bf16(af, bfr, accy, 0, 0, 0);
    }
#pragma unroll
    for (int r = 0; r < 4; r++) {
      int orow = node0 + w * 16 + q * 4 + r;
      if (orow < N_NODES) y[(size_t)orow * ODIM + m] = accy[r];
    }
  }

  __syncthreads();
  int rem = N_NODES - node0; if (rem > 64) rem = 64;
  for (int i = tid; i < 1024; i += 256) {
    int row = i >> 4, seg = i & 15;
    if (row < rem) {
      uint4 vv = *(const uint4*)(As + row * 272 + seg * 16);
      *(uint4*)((unsigned char*)outH + (size_t)(node0 + row) * 256 + seg * 16) = vv;
    }
  }
}

// ===========================================================================
// Fused: aggy = gather16(y); logits = relu((1+eps)*y + aggy + b);
// probs = softmax. Wave per node (4/block); quarters split the edge list.
// ===========================================================================
__global__ __launch_bounds__(256) void gather16_final_kernel(
    const float* __restrict__ y, const int* __restrict__ row_ptr,
    const int2* __restrict__ ep, const float* __restrict__ b,
    const float* __restrict__ eps_p, float* __restrict__ out_logits,
    float* __restrict__ out_probs) {
  int lane = threadIdx.x & 63;
  int node = blockIdx.x * 4 + (threadIdx.x >> 6);
  if (node >= N_NODES) return;
  int f = lane & 15, eq = lane >> 4;
  int a = row_ptr[node], bnd = row_ptr[node + 1];
  float acc = 0.0f;
  int j = a + eq;
  for (; j + 8 <= bnd; j += 8) {
    int s0 = ep[j].x, s1 = ep[j + 4].x;
    acc += y[(size_t)s0 * ODIM + f] + y[(size_t)s1 * ODIM + f];
  }
  for (; j < bnd; j += 4) acc += y[(size_t)ep[j].x * ODIM + f];
  acc += __shfl_xor(acc, 16, 64);
  acc += __shfl_xor(acc, 32, 64);
  if (eq == 0) {
    float epf = 1.0f + *eps_p;
    size_t idx = (size_t)node * ODIM + f;
    float logit = fmaxf(fmaf(epf, y[idx], acc) + b[f], 0.0f);
    float mx = logit;
#pragma unroll
    for (int mm = 8; mm >= 1; mm >>= 1) mx = fmaxf(mx, __shfl_xor(mx, mm, 16));
    float e = __expf(logit - mx);
    float ssum = e;
#pragma unroll
    for (int mm = 8; mm >= 1; mm >>= 1) ssum += __shfl_xor(ssum, mm, 16);
    out_logits[idx] = logit;
    out_probs[idx] = e / ssum;
  }
}

// ===========================================================================
extern "C" void kernel_launch(void* const* d_in, const int* in_sizes, int n_in,
                              void* d_out, int out_size, void* d_ws, size_t ws_size,
                              hipStream_t stream) {
  const float* x = (const float*)d_in[0];
  const int* ei = (const int*)d_in[1];       // int64 in reference -> int32 on device
  const float* ew = (const float*)d_in[2];
  const float* W0 = (const float*)d_in[3];
  const float* b0 = (const float*)d_in[4];
  const float* e0 = (const float*)d_in[5];
  const float* W1 = (const float*)d_in[6];
  const float* b1 = (const float*)d_in[7];
  const float* e1 = (const float*)d_in[8];
  const float* W2 = (const float*)d_in[9];
  const float* b2 = (const float*)d_in[10];
  const float* e2 = (const float*)d_in[11];
  float* out = (float*)d_out;

  const int* srcp = ei;
  const int* dstp = ei + N_EDGES;

  // ---- workspace layout (~97 MB; 102.4 MB proven available) ----
  char* ws = (char*)d_ws;
  size_t off = 0;
  uint32* Agg = (uint32*)(ws + off);  off += (size_t)N_NODES * DIM * 2;   // 25.6 MB
  uint32* Xb  = (uint32*)(ws + off);  off += (size_t)N_NODES * DIM * 2;   // 25.6 MB
  uint32* H   = (uint32*)(ws + off);  off += (size_t)N_NODES * DIM * 2;   // 25.6 MB
  int2* epack = (int2*)(ws + off);    off += (size_t)N_EDGES * 8;         // 12.8 MB
  float* y    = (float*)(ws + off);   off += (size_t)N_NODES * ODIM * 4;  // 6.4 MB
  int* row_ptr = (int*)(ws + off);    off += (size_t)(N_NODES + 16) * 4;
  int* bcnt   = (int*)(ws + off);     off += 2048;
  int* bbase  = (int*)(ws + off);     off += 2048;
  int* bcur   = (int*)(ws + off);     off += 2048;
  unsigned short* pW0 = (unsigned short*)(ws + off); off += 32768;
  unsigned short* pW1 = (unsigned short*)(ws + off); off += 32768;
  unsigned short* pW2 = (unsigned short*)(ws + off); off += 4096;

  // ---- independent prep: cast x, pack weights ----
  cast_x_kernel<<<(N_NODES * (DIM / 2) + 255) / 256, 256, 0, stream>>>(
      (const float2*)x, Xb);
  packW128_kernel<<<64, 256, 0, stream>>>(W0, pW0);
  packW128_kernel<<<64, 256, 0, stream>>>(W1, pW1);
  packW16_kernel<<<8, 256, 0, stream>>>(W2, pW2);

  // ---- build CSR: bucket hist -> scan -> coarse partition -> fine sort ----
  hipMemsetAsync(bcnt, 0, NB * sizeof(int), stream);
  bucket_hist_kernel<<<PBLK, 256, 0, stream>>>(dstp, bcnt);
  bucket_scan_kernel<<<1, 512, 0, stream>>>(bcnt, bbase, bcur);
  coarse_partition_kernel<<<PBLK, 256, 0, stream>>>(srcp, dstp, ew, bcur, epack);
  fine_sort_kernel<<<NB, 256, 0, stream>>>(bbase, epack, row_ptr);

  int ggrid = (N_NODES + 3) / 4;       // 25000
  int mgrid = (N_NODES + 63) / 64;     // 1563

  // layer 0: agg0 = gather(Xb); H = mlp(Xb, agg0, W0)
  gather_bf16<<<ggrid, 256, 0, stream>>>(Xb, row_ptr, epack, Agg);
  gin_mlp_mfma<0><<<mgrid, 256, 0, stream>>>(Xb, Agg, (const unsigned char*)pW0,
                                             b0, e0, H, nullptr, nullptr);
  // layer 1 (+fused layer-2 projection): agg1 = gather(H); H,y = mlp(H, agg1)
  gather_bf16<<<ggrid, 256, 0, stream>>>(H, row_ptr, epack, Agg);
  gin_mlp_mfma<1><<<mgrid, 256, 0, stream>>>(H, Agg, (const unsigned char*)pW1,
                                             b1, e1, H,
                                             (const unsigned char*)pW2, y);
  // layer 2 tail: fused gather16 + bias/relu/softmax
  gather16_final_kernel<<<ggrid, 256, 0, stream>>>(y, row_ptr, epack, b2, e2,
                                                   out, out + (size_t)N_NODES * ODIM);
}

// Round 14
// 375.563 us; speedup vs baseline: 1.1498x; 1.0493x over previous
//
#include <hip/hip_runtime.h>
#include <hip/hip_bf16.h>

#define N_NODES 100000
#define N_EDGES 1600000
#define DIM 128
#define ODIM 16
#define NB 391           // coarse buckets: node >> 8
#define PCHUNK 3200      // edges per partition/hist block
#define PBLK 500         // 500*3200 = 1.6M exactly
#define FCAP 6144        // fine-sort LDS capacity (bucket mean 4096, std 64 -> 32 sigma)
#define CAST_BLOCKS 25000  // 25000*256 = 6.4M bf16-pairs = N_NODES*64

typedef unsigned int uint32;
typedef float f32x2 __attribute__((ext_vector_type(2)));
typedef float f32x4 __attribute__((ext_vector_type(4)));
typedef short bf16x8 __attribute__((ext_vector_type(8)));

static __device__ __forceinline__ float bflo(uint32 p) { return __uint_as_float(p << 16); }
static __device__ __forceinline__ float bfhi(uint32 p) { return __uint_as_float(p & 0xFFFF0000u); }
static __device__ __forceinline__ unsigned short f2bf(float f) {
  __hip_bfloat16 h = __float2bfloat16(f);
  return *reinterpret_cast<unsigned short*>(&h);
}
static __device__ __forceinline__ uint32 pk2bf(float a, float b) {
  return (uint32)f2bf(a) | ((uint32)f2bf(b) << 16);
}

// ===========================================================================
// Fused prep: cast x -> bf16 pairs | pack W0/W1 (128x128) | pack W2 (128x16)
// | zero bcnt. One dispatch replaces 5.
// ===========================================================================
__global__ __launch_bounds__(256) void prep_kernel(
    const float2* __restrict__ x2, uint32* __restrict__ Xu,
    const float* __restrict__ W0, const float* __restrict__ W1,
    const float* __restrict__ W2,
    unsigned short* __restrict__ pW0, unsigned short* __restrict__ pW1,
    unsigned short* __restrict__ pW2, int* __restrict__ bcnt) {
  int b = blockIdx.x;
  int tid = threadIdx.x;
  if (b < CAST_BLOCKS) {
    int i = b * 256 + tid;
    float2 v = x2[i];
    Xu[i] = pk2bf(v.x, v.y);
  } else if (b < CAST_BLOCKS + 128) {
    int wsel = (b - CAST_BLOCKS) >> 6;               // 0 -> W0, 1 -> W1
    int idx = ((b - CAST_BLOCKS) & 63) * 256 + tid;  // 0..16383
    int j = idx & 7, lane = (idx >> 3) & 63, nt = (idx >> 9) & 7, kc = idx >> 12;
    const float* W = wsel ? W1 : W0;
    unsigned short* pW = wsel ? pW1 : pW0;
    pW[idx] = f2bf(W[(kc * 32 + (lane >> 4) * 8 + j) * DIM + nt * 16 + (lane & 15)]);
  } else if (b < CAST_BLOCKS + 136) {
    int idx = (b - CAST_BLOCKS - 128) * 256 + tid;   // 0..2047
    int j = idx & 7, lane = (idx >> 3) & 63, kc = idx >> 9;
    pW2[idx] = f2bf(W2[(kc * 32 + (lane >> 4) * 8 + j) * ODIM + (lane & 15)]);
  } else {
    for (int i = tid; i < NB; i += 256) bcnt[i] = 0;
  }
}

// ===========================================================================
// Coarse bucket histogram (LDS-aggregated) -> bcnt[NB].
// ===========================================================================
__global__ __launch_bounds__(256) void bucket_hist_kernel(
    const int* __restrict__ dst, int* __restrict__ bcnt) {
  __shared__ int h[NB];
  int tid = threadIdx.x;
  for (int i = tid; i < NB; i += 256) h[i] = 0;
  __syncthreads();
  int e0 = blockIdx.x * PCHUNK;
  for (int i = tid; i < PCHUNK; i += 256) atomicAdd(&h[dst[e0 + i] >> 8], 1);
  __syncthreads();
  for (int i = tid; i < NB; i += 256)
    if (h[i]) atomicAdd(&bcnt[i], h[i]);
}

// One block: exclusive scan of bcnt -> bbase, bcur.
__global__ __launch_bounds__(512) void bucket_scan_kernel(
    const int* __restrict__ bcnt, int* __restrict__ bbase,
    int* __restrict__ bcur) {
  __shared__ int sc[512];
  int t = threadIdx.x;
  int v = (t < NB) ? bcnt[t] : 0;
  sc[t] = v;
  __syncthreads();
  for (int off = 1; off < 512; off <<= 1) {
    int a = (t >= off) ? sc[t - off] : 0;
    __syncthreads();
    sc[t] += a;
    __syncthreads();
  }
  if (t < NB) {
    int base = sc[t] - v;
    bbase[t] = base;
    bcur[t] = base;
  }
}

// ===========================================================================
// Coarse partition: bin edges by (dst>>8) with LDS staging, flush run-wise
// coalesced. Entry: x = src | ((dst&255)<<20), y = bits(weight).
// ===========================================================================
__global__ __launch_bounds__(256) void coarse_partition_kernel(
    const int* __restrict__ src, const int* __restrict__ dst,
    const float* __restrict__ ew, int* __restrict__ bcur,
    int2* __restrict__ epack) {
  __shared__ int hist[NB];
  __shared__ int base_a[NB];
  __shared__ int lcur_a[NB];
  __shared__ int gbase_a[NB];
  __shared__ int2 stg[PCHUNK];
  __shared__ int gpos[PCHUNK];

  int tid = threadIdx.x;
  int e0 = blockIdx.x * PCHUNK;

  for (int i = tid; i < NB; i += 256) hist[i] = 0;
  __syncthreads();
  for (int i = tid; i < PCHUNK; i += 256) atomicAdd(&hist[dst[e0 + i] >> 8], 1);
  __syncthreads();

  // wave-0 exclusive scan over NB buckets
  if (tid < 64) {
    int run = 0;
#pragma unroll
    for (int c = 0; c < 7; c++) {
      int idx = c * 64 + tid;
      int v = (idx < NB) ? hist[idx] : 0;
      int incl = v;
#pragma unroll
      for (int off = 1; off < 64; off <<= 1) {
        int tv = __shfl_up(incl, off, 64);
        if (tid >= off) incl += tv;
      }
      if (idx < NB) base_a[idx] = run + incl - v;
      run += __shfl(incl, 63, 64);
    }
  }
  __syncthreads();
  for (int i = tid; i < NB; i += 256) {
    int c = hist[i];
    gbase_a[i] = (c > 0) ? atomicAdd(&bcur[i], c) : 0;
    lcur_a[i] = base_a[i];
  }
  __syncthreads();

  for (int i = tid; i < PCHUNK; i += 256) {
    int e = e0 + i;
    int s = src[e], d = dst[e];
    float w = ew[e];
    int b = d >> 8;
    int pos = atomicAdd(&lcur_a[b], 1);
    stg[pos] = make_int2(s | ((d & 255) << 20), __float_as_int(w));
    gpos[pos] = gbase_a[b] + (pos - base_a[b]);
  }
  __syncthreads();
  for (int i = tid; i < PCHUNK; i += 256) epack[gpos[i]] = stg[i];
}

// ===========================================================================
// Fine sort (in-place) + row_ptr build: one block per coarse bucket.
// Output entry: x = src, y = weight bits. LDS = 52.2 KB.
// ===========================================================================
__global__ __launch_bounds__(256) void fine_sort_kernel(
    const int* __restrict__ bbase, int2* __restrict__ epack,
    int* __restrict__ row_ptr) {
  __shared__ int2 ebuf[FCAP];
  __shared__ int hist[256];
  __shared__ int sc[256];
  __shared__ int cur[256];
  int tid = threadIdx.x;
  int b = blockIdx.x;
  int node0 = b << 8;
  int lo = bbase[b];
  int hi = (b == NB - 1) ? N_EDGES : bbase[b + 1];
  int n = hi - lo;
  if (n > FCAP) n = FCAP;   // statistically impossible (32 sigma)
  hist[tid] = 0;
  __syncthreads();
  for (int i = tid; i < n; i += 256) {
    int2 e = epack[lo + i];
    ebuf[i] = e;
    atomicAdd(&hist[(e.x >> 20) & 255], 1);
  }
  __syncthreads();
  sc[tid] = hist[tid];
  __syncthreads();
  for (int off = 1; off < 256; off <<= 1) {
    int a = (tid >= off) ? sc[tid - off] : 0;
    __syncthreads();
    sc[tid] += a;
    __syncthreads();
  }
  int rp = lo + sc[tid] - hist[tid];   // exclusive
  if (node0 + tid < N_NODES) row_ptr[node0 + tid] = rp;
  cur[tid] = rp;
  if (b == 0 && tid == 0) row_ptr[N_NODES] = N_EDGES;
  __syncthreads();
  for (int i = tid; i < n; i += 256) {
    int2 e = ebuf[i];
    int pos = atomicAdd(&cur[(e.x >> 20) & 255], 1);
    epack[pos] = make_int2(e.x & 0xFFFFF, e.y);
  }
}

// ===========================================================================
// Gather v4 + packed FMA: wave per node, uint4 row loads (16 lanes/row,
// 4 edges/instr), 16-edge main body with 8 vmem in flight; f32x2 accumulate
// lowers to v_pk_fma_f32 (halves FMA instruction count).
// ===========================================================================
__global__ __launch_bounds__(256) void gather_bf16(
    const uint32* __restrict__ hu, const int* __restrict__ row_ptr,
    const int2* __restrict__ ep, uint32* __restrict__ aggu) {
  int lane = threadIdx.x & 63;
  int node = blockIdx.x * 4 + (threadIdx.x >> 6);
  if (node >= N_NODES) return;
  int grp = lane >> 4, l4 = lane & 15;
  int a = row_ptr[node], bnd = row_ptr[node + 1];
  f32x2 acc2[4];
#pragma unroll
  for (int k = 0; k < 4; k++) acc2[k] = (f32x2){0.f, 0.f};

  auto acc8 = [&](float wv, const uint4& p) {
    acc2[0] += (f32x2){bflo(p.x), bfhi(p.x)} * wv;
    acc2[1] += (f32x2){bflo(p.y), bfhi(p.y)} * wv;
    acc2[2] += (f32x2){bflo(p.z), bfhi(p.z)} * wv;
    acc2[3] += (f32x2){bflo(p.w), bfhi(p.w)} * wv;
  };

  int j = a;
#pragma unroll 1
  for (; j + 16 <= bnd; j += 16) {
    int2 e0 = ep[j + grp];
    int2 e1 = ep[j + 4 + grp];
    int2 e2 = ep[j + 8 + grp];
    int2 e3 = ep[j + 12 + grp];
    uint4 p0 = *(const uint4*)(hu + (size_t)e0.x * 64 + l4 * 4);
    uint4 p1 = *(const uint4*)(hu + (size_t)e1.x * 64 + l4 * 4);
    uint4 p2 = *(const uint4*)(hu + (size_t)e2.x * 64 + l4 * 4);
    uint4 p3 = *(const uint4*)(hu + (size_t)e3.x * 64 + l4 * 4);
    acc8(__int_as_float(e0.y), p0);
    acc8(__int_as_float(e1.y), p1);
    acc8(__int_as_float(e2.y), p2);
    acc8(__int_as_float(e3.y), p3);
  }
  if (j + 8 <= bnd) {
    int2 e0 = ep[j + grp];
    int2 e1 = ep[j + 4 + grp];
    uint4 p0 = *(const uint4*)(hu + (size_t)e0.x * 64 + l4 * 4);
    uint4 p1 = *(const uint4*)(hu + (size_t)e1.x * 64 + l4 * 4);
    acc8(__int_as_float(e0.y), p0);
    acc8(__int_as_float(e1.y), p1);
    j += 8;
  }
  if (j + 4 <= bnd) {
    int2 e0 = ep[j + grp];
    uint4 p0 = *(const uint4*)(hu + (size_t)e0.x * 64 + l4 * 4);
    acc8(__int_as_float(e0.y), p0);
    j += 4;
  }
  if (j < bnd) {   // masked tail (<4 edges; bnd>=1 guaranteed here)
    int idx = j + grp;
    int vld = idx < bnd;
    int2 e = ep[vld ? idx : bnd - 1];
    uint4 p = *(const uint4*)(hu + (size_t)e.x * 64 + l4 * 4);
    float wv = vld ? __int_as_float(e.y) : 0.f;
    acc8(wv, p);
  }
#pragma unroll
  for (int k = 0; k < 4; k++) {
    acc2[k].x += __shfl_xor(acc2[k].x, 16, 64);
    acc2[k].x += __shfl_xor(acc2[k].x, 32, 64);
    acc2[k].y += __shfl_xor(acc2[k].y, 16, 64);
    acc2[k].y += __shfl_xor(acc2[k].y, 32, 64);
  }
  if (lane < 16) {
    uint4 st = {pk2bf(acc2[0].x, acc2[0].y), pk2bf(acc2[1].x, acc2[1].y),
                pk2bf(acc2[2].x, acc2[2].y), pk2bf(acc2[3].x, acc2[3].y)};
    *(uint4*)(aggu + (size_t)node * 64 + l4 * 4) = st;
  }
}

// ===========================================================================
// Fused GIN MLP via MFMA (bf16), 64 nodes x 128 outs per block.
// B fragments from global (L2-hot). uint4-vectorized staging (8 load instrs
// per tile). FUSE_PROJ=1: emit y = H_norm @ W2 only, SKIP the H copy-out
// (H1's sole consumer is the fused projection).
// ===========================================================================
template <int FUSE_PROJ>
__global__ __launch_bounds__(256) void gin_mlp_mfma(
    const uint32* Xu, const uint32* __restrict__ Au,
    const unsigned char* __restrict__ pW, const float* __restrict__ b,
    const float* __restrict__ eps_p, uint32* outH,
    const unsigned char* __restrict__ pW2, float* __restrict__ y) {
  __shared__ __align__(16) unsigned char As[64 * 272];   // 17408 B
  int tid = threadIdx.x;
  int node0 = blockIdx.x * 64;
  float epf = 1.0f + *eps_p;

  // --- staging: 1024 uint4s per tile, fully coalesced ---
  const uint4* X4 = (const uint4*)Xu;
  const uint4* A4 = (const uint4*)Au;
#pragma unroll
  for (int c = 0; c < 4; c++) {
    int t = c * 256 + tid;
    int n = t >> 4, s = t & 15;
    int node = node0 + n;
    int cn = node < N_NODES ? node : N_NODES - 1;
    uint4 xv = X4[(size_t)cn * 16 + s];
    uint4 av = A4[(size_t)cn * 16 + s];
    uint4 o;
    o.x = pk2bf(fmaf(epf, bflo(xv.x), bflo(av.x)), fmaf(epf, bfhi(xv.x), bfhi(av.x)));
    o.y = pk2bf(fmaf(epf, bflo(xv.y), bflo(av.y)), fmaf(epf, bfhi(xv.y), bfhi(av.y)));
    o.z = pk2bf(fmaf(epf, bflo(xv.z), bflo(av.z)), fmaf(epf, bfhi(xv.z), bfhi(av.z)));
    o.w = pk2bf(fmaf(epf, bflo(xv.w), bflo(av.w)), fmaf(epf, bfhi(xv.w), bfhi(av.w)));
    *(uint4*)(As + n * 272 + s * 16) = o;
  }
  __syncthreads();

  int w = tid >> 6, l = tid & 63;
  int m = l & 15, q = l >> 4;

  f32x4 acc[8];
#pragma unroll
  for (int nt = 0; nt < 8; nt++) acc[nt] = (f32x4){0.f, 0.f, 0.f, 0.f};

  const unsigned char* Abase = As + (w * 16 + m) * 272 + q * 16;
#pragma unroll
  for (int kc = 0; kc < 4; kc++) {
    bf16x8 af = *(const bf16x8*)(Abase + kc * 64);
#pragma unroll
    for (int nt = 0; nt < 8; nt++) {
      bf16x8 bfr = *(const bf16x8*)(pW + (size_t)((kc * 8 + nt) * 64 + l) * 16);
      acc[nt] = __builtin_amdgcn_mfma_f32_16x16x32_bf16(af, bfr, acc[nt], 0, 0, 0);
    }
  }

  float ss[4] = {0.f, 0.f, 0.f, 0.f};
#pragma unroll
  for (int nt = 0; nt < 8; nt++) {
    float bj = b[nt * 16 + m];
#pragma unroll
    for (int r = 0; r < 4; r++) {
      float v = fmaxf(acc[nt][r] + bj, 0.0f);
      acc[nt][r] = v;
      ss[r] += v * v;
    }
  }
#pragma unroll
  for (int r = 0; r < 4; r++) {
    float s = ss[r];
    s += __shfl_xor(s, 1, 64);
    s += __shfl_xor(s, 2, 64);
    s += __shfl_xor(s, 4, 64);
    s += __shfl_xor(s, 8, 64);
    ss[r] = 1.0f / fmaxf(sqrtf(s), 1e-12f);
  }
  // write normalized bf16 back into this wave's own As rows (in-wave DS order)
#pragma unroll
  for (int nt = 0; nt < 8; nt++) {
#pragma unroll
    for (int r = 0; r < 4; r++) {
      unsigned short hv = f2bf(acc[nt][r] * ss[r]);
      *(unsigned short*)(As + (w * 16 + q * 4 + r) * 272 + (nt * 16 + m) * 2) = hv;
    }
  }

  if (FUSE_PROJ) {
    // y = Hnorm @ W2 from this wave's own rows; H itself is dead -> no copy-out
    f32x4 accy = (f32x4){0.f, 0.f, 0.f, 0.f};
#pragma unroll
    for (int kc = 0; kc < 4; kc++) {
      bf16x8 af = *(const bf16x8*)(Abase + kc * 64);
      bf16x8 bfr = *(const bf16x8*)(pW2 + (size_t)(kc * 64 + l) * 16);
      accy = __builtin_amdgcn_mfma_f32_16x16x32_bf16(af, bfr, accy, 0, 0, 0);
    }
#pragma unroll
    for (int r = 0; r < 4; r++) {
      int orow = node0 + w * 16 + q * 4 + r;
      if (orow < N_NODES) y[(size_t)orow * ODIM + m] = accy[r];
    }
  } else {
    __syncthreads();
    int rem = N_NODES - node0; if (rem > 64) rem = 64;
    for (int i = tid; i < 1024; i += 256) {
      int row = i >> 4, seg = i & 15;
      if (row < rem) {
        uint4 vv = *(const uint4*)(As + row * 272 + seg * 16);
        *(uint4*)((unsigned char*)outH + (size_t)(node0 + row) * 256 + seg * 16) = vv;
      }
    }
  }
}

// ===========================================================================
// Fused: aggy = gather16(y); logits = relu((1+eps)*y + aggy + b);
// probs = softmax. Wave per node (4/block); quarters split the edge list.
// ===========================================================================
__global__ __launch_bounds__(256) void gather16_final_kernel(
    const float* __restrict__ y, const int* __restrict__ row_ptr,
    const int2* __restrict__ ep, const float* __restrict__ b,
    const float* __restrict__ eps_p, float* __restrict__ out_logits,
    float* __restrict__ out_probs) {
  int lane = threadIdx.x & 63;
  int node = blockIdx.x * 4 + (threadIdx.x >> 6);
  if (node >= N_NODES) return;
  int f = lane & 15, eq = lane >> 4;
  int a = row_ptr[node], bnd = row_ptr[node + 1];
  float acc = 0.0f;
  int j = a + eq;
  for (; j + 8 <= bnd; j += 8) {
    int s0 = ep[j].x, s1 = ep[j + 4].x;
    acc += y[(size_t)s0 * ODIM + f] + y[(size_t)s1 * ODIM + f];
  }
  for (; j < bnd; j += 4) acc += y[(size_t)ep[j].x * ODIM + f];
  acc += __shfl_xor(acc, 16, 64);
  acc += __shfl_xor(acc, 32, 64);
  if (eq == 0) {
    float epf = 1.0f + *eps_p;
    size_t idx = (size_t)node * ODIM + f;
    float logit = fmaxf(fmaf(epf, y[idx], acc) + b[f], 0.0f);
    float mx = logit;
#pragma unroll
    for (int mm = 8; mm >= 1; mm >>= 1) mx = fmaxf(mx, __shfl_xor(mx, mm, 16));
    float e = __expf(logit - mx);
    float ssum = e;
#pragma unroll
    for (int mm = 8; mm >= 1; mm >>= 1) ssum += __shfl_xor(ssum, mm, 16);
    out_logits[idx] = logit;
    out_probs[idx] = e / ssum;
  }
}

// ===========================================================================
extern "C" void kernel_launch(void* const* d_in, const int* in_sizes, int n_in,
                              void* d_out, int out_size, void* d_ws, size_t ws_size,
                              hipStream_t stream) {
  const float* x = (const float*)d_in[0];
  const int* ei = (const int*)d_in[1];       // int64 in reference -> int32 on device
  const float* ew = (const float*)d_in[2];
  const float* W0 = (const float*)d_in[3];
  const float* b0 = (const float*)d_in[4];
  const float* e0 = (const float*)d_in[5];
  const float* W1 = (const float*)d_in[6];
  const float* b1 = (const float*)d_in[7];
  const float* e1 = (const float*)d_in[8];
  const float* W2 = (const float*)d_in[9];
  const float* b2 = (const float*)d_in[10];
  const float* e2 = (const float*)d_in[11];
  float* out = (float*)d_out;

  const int* srcp = ei;
  const int* dstp = ei + N_EDGES;

  // ---- workspace layout (~97 MB; 102.4 MB proven available) ----
  char* ws = (char*)d_ws;
  size_t off = 0;
  uint32* Agg = (uint32*)(ws + off);  off += (size_t)N_NODES * DIM * 2;   // 25.6 MB
  uint32* Xb  = (uint32*)(ws + off);  off += (size_t)N_NODES * DIM * 2;   // 25.6 MB
  uint32* H   = (uint32*)(ws + off);  off += (size_t)N_NODES * DIM * 2;   // 25.6 MB
  int2* epack = (int2*)(ws + off);    off += (size_t)N_EDGES * 8;         // 12.8 MB
  float* y    = (float*)(ws + off);   off += (size_t)N_NODES * ODIM * 4;  // 6.4 MB
  int* row_ptr = (int*)(ws + off);    off += (size_t)(N_NODES + 16) * 4;
  int* bcnt   = (int*)(ws + off);     off += 2048;
  int* bbase  = (int*)(ws + off);     off += 2048;
  int* bcur   = (int*)(ws + off);     off += 2048;
  unsigned short* pW0 = (unsigned short*)(ws + off); off += 32768;
  unsigned short* pW1 = (unsigned short*)(ws + off); off += 32768;
  unsigned short* pW2 = (unsigned short*)(ws + off); off += 4096;

  // ---- fused prep: cast x + pack W0/W1/W2 + zero bcnt (1 dispatch) ----
  prep_kernel<<<CAST_BLOCKS + 137, 256, 0, stream>>>(
      (const float2*)x, Xb, W0, W1, W2, pW0, pW1, pW2, bcnt);

  // ---- build CSR: bucket hist -> scan -> coarse partition -> fine sort ----
  bucket_hist_kernel<<<PBLK, 256, 0, stream>>>(dstp, bcnt);
  bucket_scan_kernel<<<1, 512, 0, stream>>>(bcnt, bbase, bcur);
  coarse_partition_kernel<<<PBLK, 256, 0, stream>>>(srcp, dstp, ew, bcur, epack);
  fine_sort_kernel<<<NB, 256, 0, stream>>>(bbase, epack, row_ptr);

  int ggrid = (N_NODES + 3) / 4;       // 25000
  int mgrid = (N_NODES + 63) / 64;     // 1563

  // layer 0: agg0 = gather(Xb); H = mlp(Xb, agg0, W0)
  gather_bf16<<<ggrid, 256, 0, stream>>>(Xb, row_ptr, epack, Agg);
  gin_mlp_mfma<0><<<mgrid, 256, 0, stream>>>(Xb, Agg, (const unsigned char*)pW0,
                                             b0, e0, H, nullptr, nullptr);
  // layer 1 (+fused layer-2 projection, H1 never materialized):
  gather_bf16<<<ggrid, 256, 0, stream>>>(H, row_ptr, epack, Agg);
  gin_mlp_mfma<1><<<mgrid, 256, 0, stream>>>(H, Agg, (const unsigned char*)pW1,
                                             b1, e1, nullptr,
                                             (const unsigned char*)pW2, y);
  // layer 2 tail: fused gather16 + bias/relu/softmax
  gather16_final_kernel<<<ggrid, 256, 0, stream>>>(y, row_ptr, epack, b2, e2,
                                                   out, out + (size_t)N_NODES * ODIM);
}